// Round 4
// baseline (685.115 us; speedup 1.0000x reference)
//
#include <hip/hip_runtime.h>
#include <hip/hip_bf16.h>
#include <stdint.h>

#define HN 128      // hidden size
#define TSTEPS 250
#define ON 20       // output size
#define GK 700      // input size
#define TKK 28      // GEMM K tile (700 = 25*28 exactly)

typedef float v2f __attribute__((ext_vector_type(2)));

#define RFL(x) ((uint32_t)__builtin_amdgcn_readfirstlane((int)(x)))

// VOP3P packed fp32 FMA. All sources must be VGPR PAIRS.
// acc.{lo,hi} += b2.{lo,hi} * a2.lo   (broadcast low half of a2)
__device__ __forceinline__ void pkfma_lo(v2f& acc, v2f b2, v2f a2) {
    asm("v_pk_fma_f32 %0, %1, %2, %0 op_sel_hi:[1,0,1]"
        : "+v"(acc) : "v"(b2), "v"(a2));
}
// acc.{lo,hi} += b2.{lo,hi} * a2.hi   (broadcast high half of a2)
__device__ __forceinline__ void pkfma_hi(v2f& acc, v2f b2, v2f a2) {
    asm("v_pk_fma_f32 %0, %1, %2, %0 op_sel:[0,1,0] op_sel_hi:[1,1,1]"
        : "+v"(acc) : "v"(b2), "v"(a2));
}

// mask-driven matvec: sum_{k: bit k set} w[k]; m0..m3 are wave-uniform SGPRs,
// so each k costs ~ scalar-bit-test + s_cselect(1.0f/0) + v_fmac(sgpr, vgpr).
__device__ __forceinline__ float mv128(const float* w, uint32_t m0, uint32_t m1,
                                       uint32_t m2, uint32_t m3) {
    float q0 = 0.f, q1 = 0.f, q2 = 0.f, q3 = 0.f;
#pragma unroll
    for (int k = 0; k < 32; ++k) {
        q0 = fmaf(((m0 >> k) & 1u) ? 1.f : 0.f, w[k],      q0);
        q1 = fmaf(((m1 >> k) & 1u) ? 1.f : 0.f, w[k + 32], q1);
        q2 = fmaf(((m2 >> k) & 1u) ? 1.f : 0.f, w[k + 64], q2);
        q3 = fmaf(((m3 >> k) & 1u) ? 1.f : 0.f, w[k + 96], q3);
    }
    return (q0 + q1) + (q2 + q3);
}

// ---------------------------------------------------------------------------
// Phase A: in1_ff[bt,h] = X[bt,:] . W_ih1[h,:] + b_ih1[h]
// M=64000, N=128, K=700. Double-buffered LDS (1 barrier/tile), global->reg
// prefetch, v_pk_fma_f32 (2 fp32 FMAs/inst).
// ---------------------------------------------------------------------------
__global__ __launch_bounds__(256) void ff_gemm(const float* __restrict__ X,
                                               const float* __restrict__ W,
                                               const float* __restrict__ bias,
                                               float* __restrict__ out) {
    __shared__ __align__(16) float Xs[2][TKK][HN];
    __shared__ __align__(16) float Ws[2][TKK][HN];
    const int tid = threadIdx.x;
    const int tx = tid & 15;
    const int ty = tid >> 4;
    const int m0 = blockIdx.x * 128;

    v2f acc2[8][4];
#pragma unroll
    for (int i = 0; i < 8; ++i)
#pragma unroll
        for (int n = 0; n < 4; ++n) acc2[i][n] = (v2f){0.f, 0.f};

    float4 xr[4], wrg[4];

#define LOADT(k0)                                                              \
    {                                                                          \
        _Pragma("unroll")                                                      \
        for (int rr = 0; rr < 4; ++rr) {                                       \
            const int idx = tid + rr * 256;                                    \
            if (idx < 896) {                                                   \
                const int kb = idx >> 7, r = idx & 127;                        \
                xr[rr]  = *(const float4*)&X[(size_t)(m0 + r) * GK + (k0) + kb * 4]; \
                wrg[rr] = *(const float4*)&W[(size_t)r * GK + (k0) + kb * 4];  \
            }                                                                  \
        }                                                                      \
    }
#define STORET(buf)                                                            \
    {                                                                          \
        _Pragma("unroll")                                                      \
        for (int rr = 0; rr < 4; ++rr) {                                       \
            const int idx = tid + rr * 256;                                    \
            if (idx < 896) {                                                   \
                const int kb = idx >> 7, r = idx & 127;                        \
                Xs[buf][kb * 4 + 0][r] = xr[rr].x;                             \
                Xs[buf][kb * 4 + 1][r] = xr[rr].y;                             \
                Xs[buf][kb * 4 + 2][r] = xr[rr].z;                             \
                Xs[buf][kb * 4 + 3][r] = xr[rr].w;                             \
                Ws[buf][kb * 4 + 0][r] = wrg[rr].x;                            \
                Ws[buf][kb * 4 + 1][r] = wrg[rr].y;                            \
                Ws[buf][kb * 4 + 2][r] = wrg[rr].z;                            \
                Ws[buf][kb * 4 + 3][r] = wrg[rr].w;                            \
            }                                                                  \
        }                                                                      \
    }

    LOADT(0);
    STORET(0);
    __syncthreads();
    int cur = 0;
    for (int t = 0; t < 25; ++t) {
        if (t + 1 < 25) LOADT((t + 1) * TKK);   // issue early; hides under compute
#pragma unroll
        for (int k = 0; k < TKK; ++k) {
            v2f a2[4], b2[4];
            *(float4*)&a2[0] = *(const float4*)&Xs[cur][k][ty * 8];
            *(float4*)&a2[2] = *(const float4*)&Xs[cur][k][ty * 8 + 4];
            *(float4*)&b2[0] = *(const float4*)&Ws[cur][k][tx * 8];
            *(float4*)&b2[2] = *(const float4*)&Ws[cur][k][tx * 8 + 4];
#pragma unroll
            for (int ip = 0; ip < 4; ++ip)
#pragma unroll
                for (int n = 0; n < 4; ++n) {
                    pkfma_lo(acc2[2 * ip][n],     b2[n], a2[ip]);
                    pkfma_hi(acc2[2 * ip + 1][n], b2[n], a2[ip]);
                }
        }
        if (t + 1 < 25) STORET(cur ^ 1);        // disjoint buffer from readers
        __syncthreads();
        cur ^= 1;
    }

    float bv[8];
    *(float4*)&bv[0] = *(const float4*)&bias[tx * 8];
    *(float4*)&bv[4] = *(const float4*)&bias[tx * 8 + 4];
#pragma unroll
    for (int i = 0; i < 8; ++i) {
        const size_t row = (size_t)(m0 + ty * 8 + i);
        float4 v0, v1;
        v0.x = acc2[i][0].x + bv[0]; v0.y = acc2[i][0].y + bv[1];
        v0.z = acc2[i][1].x + bv[2]; v0.w = acc2[i][1].y + bv[3];
        v1.x = acc2[i][2].x + bv[4]; v1.y = acc2[i][2].y + bv[5];
        v1.z = acc2[i][3].x + bv[6]; v1.w = acc2[i][3].y + bv[7];
        *(float4*)&out[row * HN + tx * 8]     = v0;
        *(float4*)&out[row * HN + tx * 8 + 4] = v1;
    }
#undef LOADT
#undef STORET
}

// ---------------------------------------------------------------------------
// Phase B: spike-mask pipeline. One WG (512 thr, 8 waves) per batch row.
// Spike vectors live as 128-bit ballot masks in LDS (16 B); matvecs are
// scalar-select FMAs against register-resident weight rows -> ~zero LDS
// traffic. Roles (slot i, one barrier each):
//   waves 0-1: S1   -> s1(i)        [s1m(i-1), ff(i)]
//   waves 2-3: B    -> pB(i-1)=W_h1h2.s1(i-1) -> pBbuf
//   waves 4-5: C+L2 -> s2(i-2)      [pBbuf(i-2), s2m(i-3)]
//   wave  6  : RO   -> rdot(i-3)=W_h2o.s2(i-3)
//   wave  7  : OM   -> om/softmax(i-4)
// ---------------------------------------------------------------------------
__global__ __launch_bounds__(512, 1) void srnn_pipe2(
    const float* __restrict__ ff,
    const float* __restrict__ W_h1h1, const float* __restrict__ b_h1h1,
    const float* __restrict__ W_h1h2, const float* __restrict__ b_h1h2,
    const float* __restrict__ W_h2h2, const float* __restrict__ b_h2h2,
    const float* __restrict__ W_h2o,  const float* __restrict__ b_h2o,
    const float* __restrict__ tau_adp_h1, const float* __restrict__ tau_adp_h2,
    const float* __restrict__ tau_m_h1,   const float* __restrict__ tau_m_h2,
    const float* __restrict__ tau_m_o,
    const float* __restrict__ h1m0, const float* __restrict__ h2m0,
    const float* __restrict__ om0,
    float* __restrict__ out) {
    const int b    = blockIdx.x;
    const int tid  = threadIdx.x;
    const int w    = tid >> 6;
    const int lane = tid & 63;

    __shared__ __align__(16) unsigned long long s1m[2][2];
    __shared__ __align__(16) unsigned long long s2m[2][2];
    __shared__ __align__(16) float pBbuf[2][HN];
    __shared__ float rdot_lds[2][32];

    if (tid < 4) {
        ((unsigned long long*)s1m)[tid] = 0ULL;
        ((unsigned long long*)s2m)[tid] = 0ULL;
    }
    __syncthreads();

    if (w < 2) {
        // ================= S1: layer-1 LIF =================
        const int j = tid;
        float wA[128];
#pragma unroll
        for (int k = 0; k < 128; k += 4)
            *(float4*)&wA[k] = *(const float4*)&W_h1h1[j * HN + k];
        float h1m = h1m0[b * HN + j];
        const float a1 = expf(-1.f / tau_m_h1[j]);
        const float r1 = expf(-1.f / tau_adp_h1[j]);
        const float bias1 = b_h1h1[j];
        float b1 = 0.01f, s1p = 0.f;
        const float* ffp = ff + (size_t)b * TSTEPS * HN + j;
        float ff_c = ffp[0];
        float ff_n = ffp[HN];
        for (int i = 0; i < TSTEPS + 4; ++i) {
            if (i < TSTEPS) {
                float ff_2 = (i + 2 < TSTEPS) ? ffp[(size_t)(i + 2) * HN] : 0.f;
                uint4 mv = *(const uint4*)&s1m[(i + 1) & 1][0];   // s1(i-1)
                uint32_t m0 = RFL(mv.x), m1 = RFL(mv.y), m2 = RFL(mv.z), m3 = RFL(mv.w);
                const float pA = mv128(wA, m0, m1, m2, m3);
                b1 = r1 * b1 + (1.f - r1) * s1p;
                const float Bth = 0.01f + 1.8f * b1;
                h1m = h1m * a1 + (1.f - a1) * (ff_c + bias1 + pA) - Bth * s1p;
                const int sp = (h1m - Bth > 0.f);
                s1p = sp ? 1.f : 0.f;
                unsigned long long mk = __ballot(sp);
                if (lane == 0) s1m[i & 1][w] = mk;
                ff_c = ff_n; ff_n = ff_2;
            }
            __syncthreads();
        }
    } else if (w < 4) {
        // ================= B: pB(i-1) = W_h1h2 . s1(i-1) =================
        const int j = tid - 128;
        float wB[128];
#pragma unroll
        for (int k = 0; k < 128; k += 4)
            *(float4*)&wB[k] = *(const float4*)&W_h1h2[j * HN + k];
        for (int i = 0; i < TSTEPS + 4; ++i) {
            if (i >= 1 && i <= TSTEPS) {
                uint4 mv = *(const uint4*)&s1m[(i - 1) & 1][0];
                uint32_t m0 = RFL(mv.x), m1 = RFL(mv.y), m2 = RFL(mv.z), m3 = RFL(mv.w);
                pBbuf[(i - 1) & 1][j] = mv128(wB, m0, m1, m2, m3);
            }
            __syncthreads();
        }
    } else if (w < 6) {
        // ================= C + LIF2: s2(i-2) =================
        const int j = tid - 256;
        float wC[128];
#pragma unroll
        for (int k = 0; k < 128; k += 4)
            *(float4*)&wC[k] = *(const float4*)&W_h2h2[j * HN + k];
        float h2m = h2m0[b * HN + j];
        const float a2 = expf(-1.f / tau_m_h2[j]);
        const float r2 = expf(-1.f / tau_adp_h2[j]);
        const float bias2 = b_h1h2[j] + b_h2h2[j];
        float b2v = 0.01f, s2p = 0.f;
        for (int i = 0; i < TSTEPS + 4; ++i) {
            if (i >= 2 && i <= TSTEPS + 1) {
                const int k2 = i - 2;
                uint4 mv = *(const uint4*)&s2m[(k2 + 1) & 1][0];  // s2(k2-1)
                uint32_t m0 = RFL(mv.x), m1 = RFL(mv.y), m2 = RFL(mv.z), m3 = RFL(mv.w);
                const float pC = mv128(wC, m0, m1, m2, m3);
                const float in2 = pBbuf[k2 & 1][j] + pC + bias2;
                b2v = r2 * b2v + (1.f - r2) * s2p;
                const float Bth = 0.01f + 1.8f * b2v;
                h2m = h2m * a2 + (1.f - a2) * in2 - Bth * s2p;
                const int sp = (h2m - Bth > 0.f);
                s2p = sp ? 1.f : 0.f;
                unsigned long long mk = __ballot(sp);
                if (lane == 0) s2m[k2 & 1][w - 4] = mk;
            }
            __syncthreads();
        }
    } else if (w == 6) {
        // ================= RO: rdot(i-3) = W_h2o . s2(i-3) =================
        const int o = lane;
        float wO[128];
        const float* src = W_h2o + (size_t)((o < ON) ? o : 0) * HN;
#pragma unroll
        for (int k = 0; k < 128; k += 4)
            *(float4*)&wO[k] = *(const float4*)&src[k];
        for (int i = 0; i < TSTEPS + 4; ++i) {
            if (i >= 3 && i <= TSTEPS + 2) {
                const int k3 = i - 3;
                uint4 mv = *(const uint4*)&s2m[k3 & 1][0];
                uint32_t m0 = RFL(mv.x), m1 = RFL(mv.y), m2 = RFL(mv.z), m3 = RFL(mv.w);
                const float r = mv128(wO, m0, m1, m2, m3);
                if (o < ON) rdot_lds[k3 & 1][o] = r;
            }
            __syncthreads();
        }
    } else {
        // ================= OM: leaky readout + softmax accumulate ==========
        const int o = lane;
        float om = 0.f, ao = 0.f, bo = 0.f, acc = 0.f;
        if (o < ON) {
            om = om0[b * ON + o];
            ao = expf(-1.f / tau_m_o[o]);
            bo = b_h2o[o];
        }
        for (int i = 0; i < TSTEPS + 4; ++i) {
            if (i >= 4) {
                const int k4 = i - 4;
                if (o < ON)
                    om = om * ao + (1.f - ao) * (rdot_lds[k4 & 1][o] + bo);
                float mx = (o < ON) ? om : -3.4e38f;
#pragma unroll
                for (int m = 16; m >= 1; m >>= 1)
                    mx = fmaxf(mx, __shfl_xor(mx, m));
                float e = (o < ON) ? __expf(om - mx) : 0.f;
                float den = e;
#pragma unroll
                for (int m = 16; m >= 1; m >>= 1)
                    den += __shfl_xor(den, m);
                if (o < ON && k4 > 10) acc += e / den;
            }
            __syncthreads();
        }
        if (o < ON) out[b * ON + o] = acc;
    }
}

// ---------------------------------------------------------------------------
// Phase C: A_norm = sum|W_h1h1| + sum|W_h2h2|  -> out[5120]
// ---------------------------------------------------------------------------
__global__ void anorm_kernel(const float* __restrict__ W1,
                             const float* __restrict__ W2,
                             float* __restrict__ out) {
    __shared__ float red[256];
    float s = 0.f;
    for (int i = threadIdx.x; i < HN * HN; i += 256)
        s += fabsf(W1[i]) + fabsf(W2[i]);
    red[threadIdx.x] = s;
    __syncthreads();
    for (int off = 128; off > 0; off >>= 1) {
        if (threadIdx.x < off) red[threadIdx.x] += red[threadIdx.x + off];
        __syncthreads();
    }
    if (threadIdx.x == 0) out[256 * ON] = red[0];
}

extern "C" void kernel_launch(void* const* d_in, const int* in_sizes, int n_in,
                              void* d_out, int out_size, void* d_ws, size_t ws_size,
                              hipStream_t stream) {
    const float* input      = (const float*)d_in[0];
    // d_in[1], d_in[2]: A1_mask/A2_mask -- all-ones, unused by reference math
    const float* W_ih1      = (const float*)d_in[3];
    const float* b_ih1      = (const float*)d_in[4];
    const float* W_h1h1     = (const float*)d_in[5];
    const float* b_h1h1     = (const float*)d_in[6];
    const float* W_h1h2     = (const float*)d_in[7];
    const float* b_h1h2     = (const float*)d_in[8];
    const float* W_h2h2     = (const float*)d_in[9];
    const float* b_h2h2     = (const float*)d_in[10];
    const float* W_h2o      = (const float*)d_in[11];
    const float* b_h2o      = (const float*)d_in[12];
    const float* tau_adp_h1 = (const float*)d_in[13];
    const float* tau_adp_h2 = (const float*)d_in[14];
    const float* tau_m_h1   = (const float*)d_in[15];
    const float* tau_m_h2   = (const float*)d_in[16];
    const float* tau_m_o    = (const float*)d_in[17];
    const float* h1m0       = (const float*)d_in[18];
    const float* h2m0       = (const float*)d_in[19];
    const float* om0        = (const float*)d_in[20];

    float* out   = (float*)d_out;
    float* ffbuf = (float*)d_ws;   // 256*250*128*4 = 32.768 MB

    anorm_kernel<<<1, 256, 0, stream>>>(W_h1h1, W_h2h2, out);
    ff_gemm<<<500, 256, 0, stream>>>(input, W_ih1, b_ih1, ffbuf);
    srnn_pipe2<<<256, 512, 0, stream>>>(ffbuf, W_h1h1, b_h1h1, W_h1h2, b_h1h2,
                                        W_h2h2, b_h2h2, W_h2o, b_h2o,
                                        tau_adp_h1, tau_adp_h2,
                                        tau_m_h1, tau_m_h2, tau_m_o,
                                        h1m0, h2m0, om0, out);
}

// Round 5
// 435.468 us; speedup vs baseline: 1.5733x; 1.5733x over previous
//
#include <hip/hip_runtime.h>
#include <hip/hip_bf16.h>
#include <stdint.h>

#define HN 128      // hidden size
#define TSTEPS 250
#define ON 20       // output size
#define GK 700      // input size
#define TKK 28      // GEMM K tile (700 = 25*28 exactly)

typedef float v2f __attribute__((ext_vector_type(2)));

// VOP3P packed fp32 FMA. All sources must be VGPR PAIRS.
__device__ __forceinline__ void pkfma_lo(v2f& acc, v2f b2, v2f a2) {
    asm("v_pk_fma_f32 %0, %1, %2, %0 op_sel_hi:[1,0,1]"
        : "+v"(acc) : "v"(b2), "v"(a2));
}
__device__ __forceinline__ void pkfma_hi(v2f& acc, v2f b2, v2f a2) {
    asm("v_pk_fma_f32 %0, %1, %2, %0 op_sel:[0,1,0] op_sel_hi:[1,1,1]"
        : "+v"(acc) : "v"(b2), "v"(a2));
}

// wave-uniform lane broadcast (VALU pipe, compile-time lane index)
__device__ __forceinline__ float rlane(float v, int k) {
    return __int_as_float(__builtin_amdgcn_readlane(__float_as_int(v), k));
}

// 128-long dot: w[] in VGPRs (static idx), spike vector held wave-wide in
// slo/shi (lane l = s[l], s[64+l]). Per k: 1 v_readlane + 1 v_fmac.
__device__ __forceinline__ float mv128rl(const float* w, float slo, float shi) {
    float q0 = 0.f, q1 = 0.f, q2 = 0.f, q3 = 0.f;
#pragma unroll
    for (int k = 0; k < 64; k += 4) {
        q0 = fmaf(rlane(slo, k),     w[k],     q0);
        q1 = fmaf(rlane(slo, k + 1), w[k + 1], q1);
        q2 = fmaf(rlane(slo, k + 2), w[k + 2], q2);
        q3 = fmaf(rlane(slo, k + 3), w[k + 3], q3);
    }
#pragma unroll
    for (int k = 0; k < 64; k += 4) {
        q0 = fmaf(rlane(shi, k),     w[64 + k],     q0);
        q1 = fmaf(rlane(shi, k + 1), w[64 + k + 1], q1);
        q2 = fmaf(rlane(shi, k + 2), w[64 + k + 2], q2);
        q3 = fmaf(rlane(shi, k + 3), w[64 + k + 3], q3);
    }
    return (q0 + q1) + (q2 + q3);
}

// ---------------------------------------------------------------------------
// Phase A: in1_ff[bt,h] = X[bt,:] . W_ih1[h,:] + b_ih1[h]
// M=64000, N=128, K=700. Double-buffered LDS (1 barrier/tile), global->reg
// prefetch, v_pk_fma_f32 (2 fp32 FMAs/inst).
// ---------------------------------------------------------------------------
__global__ __launch_bounds__(256) void ff_gemm(const float* __restrict__ X,
                                               const float* __restrict__ W,
                                               const float* __restrict__ bias,
                                               float* __restrict__ out) {
    __shared__ __align__(16) float Xs[2][TKK][HN];
    __shared__ __align__(16) float Ws[2][TKK][HN];
    const int tid = threadIdx.x;
    const int tx = tid & 15;
    const int ty = tid >> 4;
    const int m0 = blockIdx.x * 128;

    v2f acc2[8][4];
#pragma unroll
    for (int i = 0; i < 8; ++i)
#pragma unroll
        for (int n = 0; n < 4; ++n) acc2[i][n] = (v2f){0.f, 0.f};

    float4 xr[4], wrg[4];

#define LOADT(k0)                                                              \
    {                                                                          \
        _Pragma("unroll")                                                      \
        for (int rr = 0; rr < 4; ++rr) {                                       \
            const int idx = tid + rr * 256;                                    \
            if (idx < 896) {                                                   \
                const int kb = idx >> 7, r = idx & 127;                        \
                xr[rr]  = *(const float4*)&X[(size_t)(m0 + r) * GK + (k0) + kb * 4]; \
                wrg[rr] = *(const float4*)&W[(size_t)r * GK + (k0) + kb * 4];  \
            }                                                                  \
        }                                                                      \
    }
#define STORET(buf)                                                            \
    {                                                                          \
        _Pragma("unroll")                                                      \
        for (int rr = 0; rr < 4; ++rr) {                                       \
            const int idx = tid + rr * 256;                                    \
            if (idx < 896) {                                                   \
                const int kb = idx >> 7, r = idx & 127;                        \
                Xs[buf][kb * 4 + 0][r] = xr[rr].x;                             \
                Xs[buf][kb * 4 + 1][r] = xr[rr].y;                             \
                Xs[buf][kb * 4 + 2][r] = xr[rr].z;                             \
                Xs[buf][kb * 4 + 3][r] = xr[rr].w;                             \
                Ws[buf][kb * 4 + 0][r] = wrg[rr].x;                            \
                Ws[buf][kb * 4 + 1][r] = wrg[rr].y;                            \
                Ws[buf][kb * 4 + 2][r] = wrg[rr].z;                            \
                Ws[buf][kb * 4 + 3][r] = wrg[rr].w;                            \
            }                                                                  \
        }                                                                      \
    }

    LOADT(0);
    STORET(0);
    __syncthreads();
    int cur = 0;
    for (int t = 0; t < 25; ++t) {
        if (t + 1 < 25) LOADT((t + 1) * TKK);   // issue early; hides under compute
#pragma unroll
        for (int k = 0; k < TKK; ++k) {
            v2f a2[4], b2[4];
            *(float4*)&a2[0] = *(const float4*)&Xs[cur][k][ty * 8];
            *(float4*)&a2[2] = *(const float4*)&Xs[cur][k][ty * 8 + 4];
            *(float4*)&b2[0] = *(const float4*)&Ws[cur][k][tx * 8];
            *(float4*)&b2[2] = *(const float4*)&Ws[cur][k][tx * 8 + 4];
#pragma unroll
            for (int ip = 0; ip < 4; ++ip)
#pragma unroll
                for (int n = 0; n < 4; ++n) {
                    pkfma_lo(acc2[2 * ip][n],     b2[n], a2[ip]);
                    pkfma_hi(acc2[2 * ip + 1][n], b2[n], a2[ip]);
                }
        }
        if (t + 1 < 25) STORET(cur ^ 1);        // disjoint buffer from readers
        __syncthreads();
        cur ^= 1;
    }

    float bv[8];
    *(float4*)&bv[0] = *(const float4*)&bias[tx * 8];
    *(float4*)&bv[4] = *(const float4*)&bias[tx * 8 + 4];
#pragma unroll
    for (int i = 0; i < 8; ++i) {
        const size_t row = (size_t)(m0 + ty * 8 + i);
        float4 v0, v1;
        v0.x = acc2[i][0].x + bv[0]; v0.y = acc2[i][0].y + bv[1];
        v0.z = acc2[i][1].x + bv[2]; v0.w = acc2[i][1].y + bv[3];
        v1.x = acc2[i][2].x + bv[4]; v1.y = acc2[i][2].y + bv[5];
        v1.z = acc2[i][3].x + bv[6]; v1.w = acc2[i][3].y + bv[7];
        *(float4*)&out[row * HN + tx * 8]     = v0;
        *(float4*)&out[row * HN + tx * 8 + 4] = v1;
    }
#undef LOADT
#undef STORET
}

// ---------------------------------------------------------------------------
// Phase B: readlane-broadcast pipeline. One WG (512 thr, 8 waves) per batch
// row. Spikes stored as floats in LDS; each consumer wave pulls them into 2
// VGPRs (2 conflict-free ds_read_b32/slot), then per-k v_readlane + v_fmac
// against register-resident weight rows. Roles (slot i, one barrier each):
//   w0,w1: S1   -> s1(i)                      [s1f(i-1), ff(i)]
//   w4,w5: B    -> pB(i-1)=W_h1h2.s1(i-1)
//   w2,w3: C+L2 -> s2(i-2)                    [pBbuf(i-2), s2f(i-3)]
//   w6   : RO   -> rdot(i-3)=W_h2o.s2(i-3)
//   w7   : OM   -> om/softmax(i-4)
// SIMD pairing (w%4): {S1lo,Blo} {S1hi,Bhi} {Clo,RO} {Chi,OM}.
// ---------------------------------------------------------------------------
__global__ __launch_bounds__(512, 1) void srnn_pipe3(
    const float* __restrict__ ff,
    const float* __restrict__ W_h1h1, const float* __restrict__ b_h1h1,
    const float* __restrict__ W_h1h2, const float* __restrict__ b_h1h2,
    const float* __restrict__ W_h2h2, const float* __restrict__ b_h2h2,
    const float* __restrict__ W_h2o,  const float* __restrict__ b_h2o,
    const float* __restrict__ tau_adp_h1, const float* __restrict__ tau_adp_h2,
    const float* __restrict__ tau_m_h1,   const float* __restrict__ tau_m_h2,
    const float* __restrict__ tau_m_o,
    const float* __restrict__ h1m0, const float* __restrict__ h2m0,
    const float* __restrict__ om0,
    float* __restrict__ out) {
    const int b    = blockIdx.x;
    const int tid  = threadIdx.x;
    const int w    = tid >> 6;
    const int lane = tid & 63;

    __shared__ __align__(16) float s1f[2][HN];
    __shared__ __align__(16) float s2f[2][HN];
    __shared__ __align__(16) float pBbuf[2][HN];
    __shared__ float rdot_lds[2][32];

    if (tid < HN) {
        s1f[0][tid] = 0.f; s1f[1][tid] = 0.f;
        s2f[0][tid] = 0.f; s2f[1][tid] = 0.f;
    }
    __syncthreads();

    if (w < 2) {
        // ================= S1: layer-1 LIF, j = w*64+lane =================
        const int j = (w << 6) + lane;
        float wA[128];
#pragma unroll
        for (int k = 0; k < 128; k += 4)
            *(float4*)&wA[k] = *(const float4*)&W_h1h1[j * HN + k];
        float h1m = h1m0[b * HN + j];
        const float a1 = expf(-1.f / tau_m_h1[j]);
        const float r1 = expf(-1.f / tau_adp_h1[j]);
        const float bias1 = b_h1h1[j];
        float b1 = 0.01f, s1p = 0.f;
        const float* ffp = ff + (size_t)b * TSTEPS * HN + j;
        float ff_c = ffp[0];
        float ff_n = ffp[HN];
        for (int i = 0; i < TSTEPS + 4; ++i) {
            if (i < TSTEPS) {
                float ff_2 = (i + 2 < TSTEPS) ? ffp[(size_t)(i + 2) * HN] : 0.f;
                const float slo = s1f[(i + 1) & 1][lane];        // s1(i-1)
                const float shi = s1f[(i + 1) & 1][64 + lane];
                const float pA = mv128rl(wA, slo, shi);
                b1 = r1 * b1 + (1.f - r1) * s1p;
                const float Bth = 0.01f + 1.8f * b1;
                h1m = h1m * a1 + (1.f - a1) * (ff_c + bias1 + pA) - Bth * s1p;
                s1p = (h1m - Bth > 0.f) ? 1.f : 0.f;
                s1f[i & 1][j] = s1p;
                ff_c = ff_n; ff_n = ff_2;
            }
            __syncthreads();
        }
    } else if (w >= 4 && w < 6) {
        // ================= B: pB(i-1) = W_h1h2 . s1(i-1) =================
        const int j = ((w - 4) << 6) + lane;
        float wB[128];
#pragma unroll
        for (int k = 0; k < 128; k += 4)
            *(float4*)&wB[k] = *(const float4*)&W_h1h2[j * HN + k];
        for (int i = 0; i < TSTEPS + 4; ++i) {
            if (i >= 1 && i <= TSTEPS) {
                const float slo = s1f[(i - 1) & 1][lane];
                const float shi = s1f[(i - 1) & 1][64 + lane];
                pBbuf[(i - 1) & 1][j] = mv128rl(wB, slo, shi);
            }
            __syncthreads();
        }
    } else if (w < 4) {
        // ================= C + LIF2: s2(i-2), j = (w-2)*64+lane ============
        const int j = ((w - 2) << 6) + lane;
        float wC[128];
#pragma unroll
        for (int k = 0; k < 128; k += 4)
            *(float4*)&wC[k] = *(const float4*)&W_h2h2[j * HN + k];
        float h2m = h2m0[b * HN + j];
        const float a2 = expf(-1.f / tau_m_h2[j]);
        const float r2 = expf(-1.f / tau_adp_h2[j]);
        const float bias2 = b_h1h2[j] + b_h2h2[j];
        float b2v = 0.01f, s2p = 0.f;
        for (int i = 0; i < TSTEPS + 4; ++i) {
            if (i >= 2 && i <= TSTEPS + 1) {
                const int k2 = i - 2;
                const float slo = s2f[(k2 + 1) & 1][lane];       // s2(k2-1)
                const float shi = s2f[(k2 + 1) & 1][64 + lane];
                const float pC = mv128rl(wC, slo, shi);
                const float in2 = pBbuf[k2 & 1][j] + pC + bias2;
                b2v = r2 * b2v + (1.f - r2) * s2p;
                const float Bth = 0.01f + 1.8f * b2v;
                h2m = h2m * a2 + (1.f - a2) * in2 - Bth * s2p;
                s2p = (h2m - Bth > 0.f) ? 1.f : 0.f;
                s2f[k2 & 1][j] = s2p;
            }
            __syncthreads();
        }
    } else if (w == 6) {
        // ================= RO: rdot(i-3) = W_h2o . s2(i-3) =================
        const int o = lane;
        float wO[128];
        const float* src = W_h2o + (size_t)((o < ON) ? o : 0) * HN;
#pragma unroll
        for (int k = 0; k < 128; k += 4)
            *(float4*)&wO[k] = *(const float4*)&src[k];
        for (int i = 0; i < TSTEPS + 4; ++i) {
            if (i >= 3 && i <= TSTEPS + 2) {
                const int k3 = i - 3;
                const float slo = s2f[k3 & 1][lane];
                const float shi = s2f[k3 & 1][64 + lane];
                const float r = mv128rl(wO, slo, shi);
                if (o < ON) rdot_lds[k3 & 1][o] = r;
            }
            __syncthreads();
        }
    } else {
        // ================= OM: leaky readout + softmax accumulate ==========
        const int o = lane;
        float om = 0.f, ao = 0.f, bo = 0.f, acc = 0.f;
        if (o < ON) {
            om = om0[b * ON + o];
            ao = expf(-1.f / tau_m_o[o]);
            bo = b_h2o[o];
        }
        for (int i = 0; i < TSTEPS + 4; ++i) {
            if (i >= 4) {
                const int k4 = i - 4;
                if (o < ON)
                    om = om * ao + (1.f - ao) * (rdot_lds[k4 & 1][o] + bo);
                float mx = (o < ON) ? om : -3.4e38f;
#pragma unroll
                for (int m = 16; m >= 1; m >>= 1)
                    mx = fmaxf(mx, __shfl_xor(mx, m));
                float e = (o < ON) ? __expf(om - mx) : 0.f;
                float den = e;
#pragma unroll
                for (int m = 16; m >= 1; m >>= 1)
                    den += __shfl_xor(den, m);
                if (o < ON && k4 > 10) acc += e / den;
            }
            __syncthreads();
        }
        if (o < ON) out[b * ON + o] = acc;
    }
}

// ---------------------------------------------------------------------------
// Phase C: A_norm = sum|W_h1h1| + sum|W_h2h2|  -> out[5120]
// ---------------------------------------------------------------------------
__global__ void anorm_kernel(const float* __restrict__ W1,
                             const float* __restrict__ W2,
                             float* __restrict__ out) {
    __shared__ float red[256];
    float s = 0.f;
    for (int i = threadIdx.x; i < HN * HN; i += 256)
        s += fabsf(W1[i]) + fabsf(W2[i]);
    red[threadIdx.x] = s;
    __syncthreads();
    for (int off = 128; off > 0; off >>= 1) {
        if (threadIdx.x < off) red[threadIdx.x] += red[threadIdx.x + off];
        __syncthreads();
    }
    if (threadIdx.x == 0) out[256 * ON] = red[0];
}

extern "C" void kernel_launch(void* const* d_in, const int* in_sizes, int n_in,
                              void* d_out, int out_size, void* d_ws, size_t ws_size,
                              hipStream_t stream) {
    const float* input      = (const float*)d_in[0];
    // d_in[1], d_in[2]: A1_mask/A2_mask -- all-ones, unused by reference math
    const float* W_ih1      = (const float*)d_in[3];
    const float* b_ih1      = (const float*)d_in[4];
    const float* W_h1h1     = (const float*)d_in[5];
    const float* b_h1h1     = (const float*)d_in[6];
    const float* W_h1h2     = (const float*)d_in[7];
    const float* b_h1h2     = (const float*)d_in[8];
    const float* W_h2h2     = (const float*)d_in[9];
    const float* b_h2h2     = (const float*)d_in[10];
    const float* W_h2o      = (const float*)d_in[11];
    const float* b_h2o      = (const float*)d_in[12];
    const float* tau_adp_h1 = (const float*)d_in[13];
    const float* tau_adp_h2 = (const float*)d_in[14];
    const float* tau_m_h1   = (const float*)d_in[15];
    const float* tau_m_h2   = (const float*)d_in[16];
    const float* tau_m_o    = (const float*)d_in[17];
    const float* h1m0       = (const float*)d_in[18];
    const float* h2m0       = (const float*)d_in[19];
    const float* om0        = (const float*)d_in[20];

    float* out   = (float*)d_out;
    float* ffbuf = (float*)d_ws;   // 256*250*128*4 = 32.768 MB

    anorm_kernel<<<1, 256, 0, stream>>>(W_h1h1, W_h2h2, out);
    ff_gemm<<<500, 256, 0, stream>>>(input, W_ih1, b_ih1, ffbuf);
    srnn_pipe3<<<256, 512, 0, stream>>>(ffbuf, W_h1h1, b_h1h1, W_h1h2, b_h1h2,
                                        W_h2h2, b_h2h2, W_h2o, b_h2o,
                                        tau_adp_h1, tau_adp_h2,
                                        tau_m_h1, tau_m_h2, tau_m_o,
                                        h1m0, h2m0, om0, out);
}